// Round 1
// baseline (227.376 us; speedup 1.0000x reference)
//
#include <hip/hip_runtime.h>
#include <math.h>

// Problem constants (from reference)
#define NUM_C 9
constexpr float BASE_SMOOTH = 0.1f;
constexpr float W_BASE = BASE_SMOOTH / (float)NUM_C;   // 0.011111
constexpr float W_MAIN = 0.7f;                          // 1 - 0.1 - 0.2

constexpr int THREADS = 256;
constexpr int ROWS_PER_BLOCK = 1024;                    // 9216 floats = 2304 float4 = 9/thread
constexpr int FLOATS_PER_BLOCK = ROWS_PER_BLOCK * NUM_C;
constexpr int VEC_PER_THREAD = FLOATS_PER_BLOCK / 4 / THREADS;  // 9
constexpr int ROWS_PER_THREAD = ROWS_PER_BLOCK / THREADS;       // 4

__global__ __launch_bounds__(THREADS) void ccel_main(
    const float* __restrict__ logits,
    const int* __restrict__ targets,
    float* __restrict__ partials,
    int nRows)
{
    __shared__ float lds[FLOATS_PER_BLOCK];
    __shared__ float wave_sums[THREADS / 64];

    const int tid = threadIdx.x;
    const long long totalVecs = ((long long)nRows * NUM_C) / 4;  // 9e6, exact
    const long long vecBase = (long long)blockIdx.x * (FLOATS_PER_BLOCK / 4);

    const float4* __restrict__ gv = (const float4*)logits;
    float4* ldsv = (float4*)lds;

    // Stage 1024 rows into LDS with coalesced 16B loads.
#pragma unroll
    for (int i = 0; i < VEC_PER_THREAD; i++) {
        long long vi = vecBase + (long long)(i * THREADS + tid);
        if (vi < totalVecs) {
            ldsv[i * THREADS + tid] = gv[vi];
        }
    }
    __syncthreads();

    const int rowBase = blockIdx.x * ROWS_PER_BLOCK;
    float acc = 0.0f;

#pragma unroll
    for (int i = 0; i < ROWS_PER_THREAD; i++) {
        const int lr = tid + i * THREADS;       // local row
        const int r = rowBase + lr;             // global row
        if (r < nRows) {
            const float* x = &lds[lr * NUM_C];
            const int t = targets[r];           // coalesced across lanes

            // max for stable lse
            float m = x[0];
#pragma unroll
            for (int j = 1; j < NUM_C; j++) m = fmaxf(m, x[j]);

            float s = 0.0f;
            float weighted = 0.0f;
#pragma unroll
            for (int j = 0; j < NUM_C; j++) {
                const float xj = x[j];
                s += __expf(xj - m);
                const int d = j - t;
                float w;
                if (d == 0)      w = W_MAIN;
                else if (d > 0)  w = W_BASE + 0.2f * exp2f((float)(-d));
                else             w = W_BASE;
                weighted += w * xj;
            }
            const float lse = m + __logf(s);
            // S(t) = 0.7 + 8*base + 0.2*(1 - 2^(t-8)) = 0.9888889 - 0.2*2^(t-8)
            const float S = 0.98888889f - 0.2f * exp2f((float)(t - 8));
            acc += lse - weighted / S;
        }
    }

    // wave reduce (64 lanes)
#pragma unroll
    for (int off = 32; off > 0; off >>= 1)
        acc += __shfl_down(acc, off, 64);

    if ((tid & 63) == 0) wave_sums[tid >> 6] = acc;
    __syncthreads();
    if (tid == 0) {
        float bsum = 0.0f;
#pragma unroll
        for (int w = 0; w < THREADS / 64; w++) bsum += wave_sums[w];
        partials[blockIdx.x] = bsum;
    }
}

__global__ __launch_bounds__(THREADS) void ccel_finish(
    const float* __restrict__ partials,
    int n,
    float* __restrict__ out,
    float invBatch)
{
    double acc = 0.0;
    for (int i = threadIdx.x; i < n; i += THREADS)
        acc += (double)partials[i];

#pragma unroll
    for (int off = 32; off > 0; off >>= 1)
        acc += __shfl_down(acc, off, 64);

    __shared__ double wave_sums[THREADS / 64];
    if ((threadIdx.x & 63) == 0) wave_sums[threadIdx.x >> 6] = acc;
    __syncthreads();
    if (threadIdx.x == 0) {
        double total = 0.0;
#pragma unroll
        for (int w = 0; w < THREADS / 64; w++) total += wave_sums[w];
        out[0] = (float)(total * (double)invBatch);
    }
}

extern "C" void kernel_launch(void* const* d_in, const int* in_sizes, int n_in,
                              void* d_out, int out_size, void* d_ws, size_t ws_size,
                              hipStream_t stream) {
    const float* logits = (const float*)d_in[0];
    const int* targets = (const int*)d_in[1];
    const int nRows = in_sizes[1];              // 4,000,000

    float* partials = (float*)d_ws;
    const int nBlocks = (nRows + ROWS_PER_BLOCK - 1) / ROWS_PER_BLOCK;  // 3907

    ccel_main<<<nBlocks, THREADS, 0, stream>>>(logits, targets, partials, nRows);
    ccel_finish<<<1, THREADS, 0, stream>>>(partials, nBlocks, (float*)d_out,
                                           1.0f / (float)nRows);
}

// Round 2
// 213.884 us; speedup vs baseline: 1.0631x; 1.0631x over previous
//
#include <hip/hip_runtime.h>
#include <math.h>

#define NUM_C 9
constexpr float W_BASE = 0.1f / 9.0f;     // 0.0111111
constexpr float W_MAIN = 0.7f;            // 1 - 0.1 - 0.2

constexpr int THREADS = 256;
constexpr int ROWS_PER_BLOCK = 1024;                       // 4 rows/thread
constexpr int VECS_PER_BLOCK = ROWS_PER_BLOCK * NUM_C / 4; // 2304 float4
constexpr int VECS_PER_WAVE = VECS_PER_BLOCK / 4;          // 576
constexpr int CALLS_PER_WAVE = VECS_PER_WAVE / 64;         // 9

__device__ __forceinline__ void async_copy16(const float4* g, float4* l) {
    __builtin_amdgcn_global_load_lds(
        (const __attribute__((address_space(1))) void*)g,
        (__attribute__((address_space(3))) void*)l,
        16 /*bytes*/, 0 /*offset*/, 0 /*aux*/);
}

__global__ __launch_bounds__(THREADS, 4) void ccel_main(
    const float* __restrict__ logits,
    const int* __restrict__ targets,
    float* __restrict__ partials,
    int nRows, int nFullBlocks)
{
    __shared__ float4 lds4[VECS_PER_BLOCK];   // 36 KB -> 4 blocks/CU
    __shared__ float wave_sums[THREADS / 64];

    const int tid = threadIdx.x;
    const int wave = tid >> 6;
    const int lane = tid & 63;
    const long long vecBase = (long long)blockIdx.x * VECS_PER_BLOCK;
    const float4* gv = (const float4*)logits + vecBase;

    if (blockIdx.x < nFullBlocks) {
        // Direct global->LDS DMA, 16B per lane, perfectly linear layout.
        const float4* src = gv + wave * VECS_PER_WAVE;
        float4* dst = lds4 + wave * VECS_PER_WAVE;
#pragma unroll
        for (int i = 0; i < CALLS_PER_WAVE; i++) {
            async_copy16(src + i * 64 + lane, dst + i * 64);
        }
    } else {
        // Tail block: guarded VGPR path.
        const long long totalVecs = ((long long)nRows * NUM_C) / 4;
        for (int i = tid; i < VECS_PER_BLOCK; i += THREADS) {
            if (vecBase + i < totalVecs) lds4[i] = gv[i];
        }
    }
    __syncthreads();   // emits s_waitcnt vmcnt(0) covering the async loads

    const int myRow = blockIdx.x * ROWS_PER_BLOCK + tid * 4;
    float acc = 0.0f;

    if (myRow < nRows) {   // tail rows come in whole multiples of 4 per thread
        // 4 targets, one 16B coalesced load
        const int4 t4 = ((const int4*)targets)[myRow >> 2];
        const int tg[4] = {t4.x, t4.y, t4.z, t4.w};

        // 36 consecutive floats (4 rows) via 9 ds_read_b128
        float x[36];
        float4* xv = (float4*)x;
#pragma unroll
        for (int i = 0; i < 9; i++) xv[i] = lds4[tid * 9 + i];

#pragma unroll
        for (int k = 0; k < 4; k++) {
            const float* xr = x + k * NUM_C;
            const int t = tg[k];

            // max for stable lse
            float m = xr[0];
#pragma unroll
            for (int j = 1; j < NUM_C; j++) m = fmaxf(m, xr[j]);

            // sum of logits + x[t] select
            float sum = 0.0f, xt = 0.0f;
#pragma unroll
            for (int j = 0; j < NUM_C; j++) {
                sum += xr[j];
                xt = (t == j) ? xr[j] : xt;
            }

            // G(t) = sum_{j>t} 2^(t-j) x[j] via backward halving scan
            float g = 0.0f, gt = 0.0f;
#pragma unroll
            for (int j = NUM_C - 1; j >= 1; j--) {
                g = 0.5f * (xr[j] + g);
                gt = (t == j - 1) ? g : gt;
            }

            // softmax denominator
            float es = 0.0f;
#pragma unroll
            for (int j = 0; j < NUM_C; j++) es += __expf(xr[j] - m);
            const float lse = m + __logf(es);

            // S(t) = 0.9888889 - 0.2 * 2^(t-8); v_ldexp + v_rcp, no div
            const float S = 0.98888889f - 0.2f * ldexpf(1.0f, t - 8);
            const float weighted = W_BASE * sum + (W_MAIN - W_BASE) * xt + 0.2f * gt;
            acc += lse - weighted * __builtin_amdgcn_rcpf(S);
        }
    }

    // wave reduce (64 lanes)
#pragma unroll
    for (int off = 32; off > 0; off >>= 1)
        acc += __shfl_down(acc, off, 64);

    if (lane == 0) wave_sums[wave] = acc;
    __syncthreads();
    if (tid == 0) {
        float bsum = 0.0f;
#pragma unroll
        for (int w = 0; w < THREADS / 64; w++) bsum += wave_sums[w];
        partials[blockIdx.x] = bsum;
    }
}

__global__ __launch_bounds__(1024) void ccel_finish(
    const float* __restrict__ partials,
    int n,
    float* __restrict__ out,
    float invBatch)
{
    double acc = 0.0;
    for (int i = threadIdx.x; i < n; i += 1024)
        acc += (double)partials[i];

#pragma unroll
    for (int off = 32; off > 0; off >>= 1)
        acc += __shfl_down(acc, off, 64);

    __shared__ double wsum[16];
    if ((threadIdx.x & 63) == 0) wsum[threadIdx.x >> 6] = acc;
    __syncthreads();
    if (threadIdx.x == 0) {
        double total = 0.0;
#pragma unroll
        for (int w = 0; w < 16; w++) total += wsum[w];
        out[0] = (float)(total * (double)invBatch);
    }
}

extern "C" void kernel_launch(void* const* d_in, const int* in_sizes, int n_in,
                              void* d_out, int out_size, void* d_ws, size_t ws_size,
                              hipStream_t stream) {
    const float* logits = (const float*)d_in[0];
    const int* targets = (const int*)d_in[1];
    const int nRows = in_sizes[1];                 // 4,000,000

    float* partials = (float*)d_ws;
    const int nBlocks = (nRows + ROWS_PER_BLOCK - 1) / ROWS_PER_BLOCK;   // 3907
    const long long totalVecs = ((long long)nRows * NUM_C) / 4;
    const int nFullBlocks = (int)(totalVecs / VECS_PER_BLOCK);           // 3906

    ccel_main<<<nBlocks, THREADS, 0, stream>>>(logits, targets, partials,
                                               nRows, nFullBlocks);
    ccel_finish<<<1, 1024, 0, stream>>>(partials, nBlocks, (float*)d_out,
                                        1.0f / (float)nRows);
}